// Round 7
// baseline (3006.540 us; speedup 1.0000x reference)
//
#include <hip/hip_runtime.h>
#include <hip/hip_cooperative_groups.h>
#include <math.h>

namespace cg = cooperative_groups;

#define N_NODES 2048
#define HID 64
#define BATCH 8
#define SEQ 32
#define CAP 128          // ELL slots per row (nnz/row ~33, padded to x8)
#define TB 256           // SEQ*BATCH
#define NH (N_NODES*HID) // 131072 per batch

typedef __attribute__((ext_vector_type(8))) _Float16 half8;

__device__ __forceinline__ float fast_sig(float s) {
  return 1.f / (1.f + __expf(-s));
}
__device__ __forceinline__ float fast_tanh(float s) {
  float e = __expf(-2.f * fabsf(s));
  float t = 1.f - 2.f * e / (1.f + e);
  return copysignf(t, s);
}

// ---------------- Kernel 0: build padded ELL (colh = col*HID) ---------------
__global__ __launch_bounds__(256) void k_build_ell(
    const float* __restrict__ L, float* __restrict__ ell_val,
    int* __restrict__ ell_colh, int* __restrict__ ell_cnt) {
  int wave = (blockIdx.x * blockDim.x + threadIdx.x) >> 6;
  int lane = threadIdx.x & 63;
  if (wave >= N_NODES) return;
  const float* row = L + (size_t)wave * N_NODES;
  int base = 0;
  for (int c = 0; c < N_NODES / 64; ++c) {
    int col = c * 64 + lane;
    float v = row[col];
    bool nz = (v != 0.0f);
    unsigned long long mask = __ballot(nz);
    int before = __popcll(mask & ((1ull << lane) - 1ull));
    if (nz) {
      int slot = base + before;
      if (slot < CAP) {
        ell_colh[wave * CAP + slot] = col * HID;
        ell_val[wave * CAP + slot] = v;
      }
    }
    base += __popcll(mask);
  }
  if (base > CAP) base = CAP;
  int pad = (base + 7) & ~7;
  if (pad > CAP) pad = CAP;
  for (int s = base + lane; s < pad; s += 64) {
    ell_colh[wave * CAP + s] = 0;
    ell_val[wave * CAP + s] = 0.f;
  }
  if (lane == 0) ell_cnt[wave] = pad;
}

// ---------------- Transpose x[b][t][n] -> xT[n][tb],  tb = t*8 + b ----------
__global__ __launch_bounds__(256) void k_xt(const float* __restrict__ x,
                                            float* __restrict__ xT) {
  __shared__ float s[32][65];
  int n0  = (blockIdx.x & 63) * 32;
  int tb0 = (blockIdx.x >> 6) * 64;
  for (int idx = threadIdx.x; idx < 32 * 64; idx += 256) {
    int ln = idx & 31, ltb = idx >> 5;
    int tb = tb0 + ltb; int b = tb & 7, t = tb >> 3;
    s[ln][ltb] = x[((size_t)b * SEQ + t) * N_NODES + n0 + ln];
  }
  __syncthreads();
  for (int idx = threadIdx.x; idx < 32 * 64; idx += 256) {
    int ln = idx >> 6, ltb = idx & 63;
    xT[(size_t)(n0 + ln) * TB + tb0 + ltb] = s[ln][ltb];
  }
}

// ---------------- LxT[m][tb] = sum_n L[m,n] * xT[n][tb] ---------------------
__global__ __launch_bounds__(512) void k_spmm_x(
    const float* __restrict__ xT, const float* __restrict__ ell_val,
    const int* __restrict__ ell_colh, const int* __restrict__ ell_cnt,
    float* __restrict__ LxT) {
  int m = (blockIdx.x * blockDim.x + threadIdx.x) >> 6;
  int lane = threadIdx.x & 63;
  if (m >= N_NODES) return;
  const int* cp = ell_colh + m * CAP;
  const float* vp = ell_val + m * CAP;
  int cnt = ell_cnt[m];
  float4 acc = {0.f, 0.f, 0.f, 0.f};
  for (int k = 0; k < cnt; k += 4) {
    int4 c = *(const int4*)(cp + k);
    float4 v = *(const float4*)(vp + k);
    float4 xa = *(const float4*)&xT[(size_t)c.x * 4 + lane * 4];
    float4 xb = *(const float4*)&xT[(size_t)c.y * 4 + lane * 4];
    float4 xc = *(const float4*)&xT[(size_t)c.z * 4 + lane * 4];
    float4 xd = *(const float4*)&xT[(size_t)c.w * 4 + lane * 4];
    acc.x = fmaf(v.x, xa.x, acc.x); acc.y = fmaf(v.x, xa.y, acc.y);
    acc.z = fmaf(v.x, xa.z, acc.z); acc.w = fmaf(v.x, xa.w, acc.w);
    acc.x = fmaf(v.y, xb.x, acc.x); acc.y = fmaf(v.y, xb.y, acc.y);
    acc.z = fmaf(v.y, xb.z, acc.z); acc.w = fmaf(v.y, xb.w, acc.w);
    acc.x = fmaf(v.z, xc.x, acc.x); acc.y = fmaf(v.z, xc.y, acc.y);
    acc.z = fmaf(v.z, xc.z, acc.z); acc.w = fmaf(v.z, xc.w, acc.w);
    acc.x = fmaf(v.w, xd.x, acc.x); acc.y = fmaf(v.w, xd.y, acc.y);
    acc.z = fmaf(v.w, xd.z, acc.z); acc.w = fmaf(v.w, xd.w, acc.w);
  }
  *(float4*)&LxT[(size_t)m * TB + lane * 4] = acc;
}

// ---------------- Persistent kernel: all 32 steps, grid-wide sync -----------
// 256 blocks (= #CUs, co-residency guaranteed) x 512 threads. One wave = one
// row m, all 8 batches (half8 gather, round-5 structure). Dense phase in two
// 4-batch nibbles sharing sdiff (keeps LDS at 57.5KB < 64KB).
__global__ __launch_bounds__(512, 2) void k_steps(
    half8* __restrict__ stA, half8* __restrict__ stB,
    const float* __restrict__ LxT, const float* __restrict__ ell_val,
    const int* __restrict__ ell_colh, const int* __restrict__ ell_cnt,
    const float* __restrict__ Wg, const float* __restrict__ bg,
    const float* __restrict__ Wc, const float* __restrict__ bc,
    half8* __restrict__ rspk, half8* __restrict__ upk,
    float* __restrict__ out) {
  cg::grid_group grid = cg::this_grid();
  __shared__ float4 sWg[128][16];   // 32KB
  __shared__ float4 sWc[64][16];    // 16KB
  __shared__ float sWgx[128], sbg[128], sWcx[64], sbc[64];
  __shared__ float sdiff[8][4][64]; // 8KB, wave-private rows
  for (int idx = threadIdx.x; idx < 128 * 16; idx += 512) {
    int o = idx >> 4, p = idx & 15, j = p ^ (o & 15);
    const float* src = Wg + o * 65 + 1 + j * 4;
    sWg[o][p] = make_float4(src[0], src[1], src[2], src[3]);
  }
  for (int idx = threadIdx.x; idx < 64 * 16; idx += 512) {
    int o = idx >> 4, p = idx & 15, j = p ^ (o & 15);
    const float* src = Wc + o * 65 + 1 + j * 4;
    sWc[o][p] = make_float4(src[0], src[1], src[2], src[3]);
  }
  if (threadIdx.x < 128) {
    sWgx[threadIdx.x] = Wg[threadIdx.x * 65];
    sbg[threadIdx.x]  = bg[threadIdx.x];
  } else if (threadIdx.x < 192) {
    int o = threadIdx.x - 128;
    sWcx[o] = Wc[o * 65];
    sbc[o]  = bc[o];
  }
  __syncthreads();

  int wv = threadIdx.x >> 6, lane = threadIdx.x & 63;
  int m = blockIdx.x * 8 + wv;
  const int* cp = ell_colh + m * CAP;
  const float* vp = ell_val + m * CAP;
  int cnt = ell_cnt[m];
  int o0 = lane, o1 = lane + 64, sw = lane & 15;
  float wx0 = sWgx[o0], bg0 = sbg[o0];
  float wx1 = sWgx[o1], bg1 = sbg[o1];
  float wxc = sWcx[lane], bbc = sbc[lane];

  half8* cur = stA;
  half8* nxt = stB;
  for (int t = 0; t < SEQ; ++t) {
    // ---------------- phase A: gates -> rs / u ----------------
    const half8* pk = cur + lane;
    float acc0=0.f,acc1=0.f,acc2=0.f,acc3=0.f,acc4=0.f,acc5=0.f,acc6=0.f,acc7=0.f;
    for (int k = 0; k < cnt; k += 8) {
      int4 ca = *(const int4*)(cp + k);
      int4 cb = *(const int4*)(cp + k + 4);
      float4 va = *(const float4*)(vp + k);
      float4 vb = *(const float4*)(vp + k + 4);
#define GATH(C, V) { half8 hv = pk[C]; \
      acc0 = fmaf(V, (float)hv[0], acc0); acc1 = fmaf(V, (float)hv[1], acc1); \
      acc2 = fmaf(V, (float)hv[2], acc2); acc3 = fmaf(V, (float)hv[3], acc3); \
      acc4 = fmaf(V, (float)hv[4], acc4); acc5 = fmaf(V, (float)hv[5], acc5); \
      acc6 = fmaf(V, (float)hv[6], acc6); acc7 = fmaf(V, (float)hv[7], acc7); }
      GATH(ca.x, va.x) GATH(ca.y, va.y) GATH(ca.z, va.z) GATH(ca.w, va.w)
      GATH(cb.x, vb.x) GATH(cb.y, vb.y) GATH(cb.z, vb.z) GATH(cb.w, vb.w)
#undef GATH
    }
    float4 LxLo = *(const float4*)&LxT[(size_t)m * TB + t * BATCH];
    float4 LxHi = *(const float4*)&LxT[(size_t)m * TB + t * BATCH + 4];
    float Lx8[8] = {LxLo.x, LxLo.y, LxLo.z, LxLo.w,
                    LxHi.x, LxHi.y, LxHi.z, LxHi.w};
    float s0[8], s1[8];
    #pragma unroll
    for (int b = 0; b < 8; ++b) {
      s0[b] = fmaf(Lx8[b], wx0, bg0);
      s1[b] = fmaf(Lx8[b], wx1, bg1);
    }
    // nibble 0: batches 0..3
    sdiff[wv][0][lane] = acc0; sdiff[wv][1][lane] = acc1;
    sdiff[wv][2][lane] = acc2; sdiff[wv][3][lane] = acc3;
    #pragma unroll
    for (int j = 0; j < 16; ++j) {
      float4 w0 = sWg[o0][j ^ sw];
      float4 w1 = sWg[o1][j ^ sw];
      #pragma unroll
      for (int b = 0; b < 4; ++b) {
        const float4 d = *(const float4*)&sdiff[wv][b][j * 4];  // broadcast
        s0[b] += d.x * w0.x + d.y * w0.y + d.z * w0.z + d.w * w0.w;
        s1[b] += d.x * w1.x + d.y * w1.y + d.z * w1.z + d.w * w1.w;
      }
    }
    // nibble 1: batches 4..7 (wave-private reuse; lgkmcnt orders RAW/WAR)
    sdiff[wv][0][lane] = acc4; sdiff[wv][1][lane] = acc5;
    sdiff[wv][2][lane] = acc6; sdiff[wv][3][lane] = acc7;
    #pragma unroll
    for (int j = 0; j < 16; ++j) {
      float4 w0 = sWg[o0][j ^ sw];
      float4 w1 = sWg[o1][j ^ sw];
      #pragma unroll
      for (int b = 0; b < 4; ++b) {
        const float4 d = *(const float4*)&sdiff[wv][b][j * 4];
        s0[b + 4] += d.x * w0.x + d.y * w0.y + d.z * w0.z + d.w * w0.w;
        s1[b + 4] += d.x * w1.x + d.y * w1.y + d.z * w1.z + d.w * w1.w;
      }
    }
    if (m < N_NODES / 2) {
      // r-half: flat gate idx == flat state idx (rep0->node 2m, rep1->2m+1)
      half8 sp0 = pk[(size_t)m * 128];
      half8 sp1 = pk[(size_t)m * 128 + 64];
      half8 r0, r1;
      #pragma unroll
      for (int b = 0; b < 8; ++b) {
        r0[b] = (_Float16)(fast_sig(s0[b]) * (float)sp0[b]);
        r1[b] = (_Float16)(fast_sig(s1[b]) * (float)sp1[b]);
      }
      half8* rp = rspk + lane;
      rp[(size_t)m * 128] = r0;
      rp[(size_t)m * 128 + 64] = r1;
    } else {
      int mm = m - N_NODES / 2;
      half8 u0, u1;
      #pragma unroll
      for (int b = 0; b < 8; ++b) {
        u0[b] = (_Float16)fast_sig(s0[b]);
        u1[b] = (_Float16)fast_sig(s1[b]);
      }
      half8* up2 = upk + lane;
      up2[(size_t)mm * 128] = u0;
      up2[(size_t)mm * 128 + 64] = u1;
    }
    grid.sync();
    // ---------------- phase B: cand + GRU update ----------------
    const half8* rk = rspk + lane;
    acc0=0.f; acc1=0.f; acc2=0.f; acc3=0.f; acc4=0.f; acc5=0.f; acc6=0.f; acc7=0.f;
    for (int k = 0; k < cnt; k += 8) {
      int4 ca = *(const int4*)(cp + k);
      int4 cb = *(const int4*)(cp + k + 4);
      float4 va = *(const float4*)(vp + k);
      float4 vb = *(const float4*)(vp + k + 4);
#define GATH(C, V) { half8 hv = rk[C]; \
      acc0 = fmaf(V, (float)hv[0], acc0); acc1 = fmaf(V, (float)hv[1], acc1); \
      acc2 = fmaf(V, (float)hv[2], acc2); acc3 = fmaf(V, (float)hv[3], acc3); \
      acc4 = fmaf(V, (float)hv[4], acc4); acc5 = fmaf(V, (float)hv[5], acc5); \
      acc6 = fmaf(V, (float)hv[6], acc6); acc7 = fmaf(V, (float)hv[7], acc7); }
      GATH(ca.x, va.x) GATH(ca.y, va.y) GATH(ca.z, va.z) GATH(ca.w, va.w)
      GATH(cb.x, vb.x) GATH(cb.y, vb.y) GATH(cb.z, vb.z) GATH(cb.w, vb.w)
#undef GATH
    }
    float s[8];
    #pragma unroll
    for (int b = 0; b < 8; ++b) s[b] = fmaf(Lx8[b], wxc, bbc);
    sdiff[wv][0][lane] = acc0; sdiff[wv][1][lane] = acc1;
    sdiff[wv][2][lane] = acc2; sdiff[wv][3][lane] = acc3;
    #pragma unroll
    for (int j = 0; j < 16; ++j) {
      float4 w = sWc[lane][j ^ sw];
      #pragma unroll
      for (int b = 0; b < 4; ++b) {
        const float4 d = *(const float4*)&sdiff[wv][b][j * 4];
        s[b] += d.x * w.x + d.y * w.y + d.z * w.z + d.w * w.w;
      }
    }
    sdiff[wv][0][lane] = acc4; sdiff[wv][1][lane] = acc5;
    sdiff[wv][2][lane] = acc6; sdiff[wv][3][lane] = acc7;
    #pragma unroll
    for (int j = 0; j < 16; ++j) {
      float4 w = sWc[lane][j ^ sw];
      #pragma unroll
      for (int b = 0; b < 4; ++b) {
        const float4 d = *(const float4*)&sdiff[wv][b][j * 4];
        s[b + 4] += d.x * w.x + d.y * w.y + d.z * w.z + d.w * w.w;
      }
    }
    half8 hp = pk[(size_t)m * 64];
    half8 uu = (upk + lane)[(size_t)m * 64];
    half8 np;
    float* op = out + (size_t)t * BATCH * NH + m * HID + lane;
    #pragma unroll
    for (int b = 0; b < 8; ++b) {
      float u = (float)uu[b];
      float nh = u * (float)hp[b] + (1.f - u) * fast_tanh(s[b]);
      np[b] = (_Float16)nh;
      op[(size_t)b * NH] = nh;
    }
    (nxt + lane)[(size_t)m * 64] = np;
    half8* tmp = cur; cur = nxt; nxt = tmp;
    if (t != SEQ - 1) grid.sync();
  }
}

extern "C" void kernel_launch(void* const* d_in, const int* in_sizes, int n_in,
                              void* d_out, int out_size, void* d_ws, size_t ws_size,
                              hipStream_t stream) {
  const float* x  = (const float*)d_in[0];
  const float* L  = (const float*)d_in[1];
  const float* Wg = (const float*)d_in[2];
  const float* bg = (const float*)d_in[3];
  const float* Wc = (const float*)d_in[4];
  const float* bc = (const float*)d_in[5];
  float* out = (float*)d_out;
  float* ws = (float*)d_ws;

  float* ell_val  = ws;                                     // N*CAP f
  int*   ell_colh = (int*)(ws + (size_t)N_NODES * CAP);     // N*CAP i
  int*   ell_cnt  = (int*)(ws + (size_t)2 * N_NODES * CAP); // N i
  float* xT    = ws + (size_t)2 * N_NODES * CAP + N_NODES;  // N*TB f
  float* LxT   = xT + (size_t)N_NODES * TB;                 // N*TB f
  float* fend  = LxT + (size_t)N_NODES * TB;
  half8* stA  = (half8*)fend;                               // N*64 half8 = 2MB
  half8* stB  = stA + (size_t)N_NODES * HID;
  half8* rspk = stB + (size_t)N_NODES * HID;
  half8* upk  = rspk + (size_t)N_NODES * HID;

  k_build_ell<<<N_NODES / 4, 256, 0, stream>>>(L, ell_val, ell_colh, ell_cnt);
  k_xt<<<256, 256, 0, stream>>>(x, xT);
  k_spmm_x<<<N_NODES / 8, 512, 0, stream>>>(xT, ell_val, ell_colh, ell_cnt, LxT);
  hipMemsetAsync(stA, 0, (size_t)N_NODES * HID * sizeof(half8), stream);

  half8* stA_p = stA; half8* stB_p = stB;
  const float* LxT_p = LxT;
  const float* ev_p = ell_val; const int* ec_p = ell_colh;
  const int* en_p = ell_cnt;
  const float* Wg_p = Wg; const float* bg_p = bg;
  const float* Wc_p = Wc; const float* bc_p = bc;
  half8* rs_p = rspk; half8* u_p = upk;
  float* out_p = out;
  void* args[] = {&stA_p, &stB_p, &LxT_p, &ev_p, &ec_p, &en_p,
                  &Wg_p, &bg_p, &Wc_p, &bc_p, &rs_p, &u_p, &out_p};
  hipLaunchCooperativeKernel((const void*)k_steps, dim3(256), dim3(512),
                             args, 0, stream);
}

// Round 8
// 814.594 us; speedup vs baseline: 3.6908x; 3.6908x over previous
//
#include <hip/hip_runtime.h>
#include <math.h>

#define N_NODES 2048
#define HID 64
#define BATCH 8
#define SEQ 32
#define CAP 64           // ELL slots per row (nnz/row ~33, max ~55, padded x8)
#define TB 256           // SEQ*BATCH
#define NH (N_NODES*HID) // 131072 per batch
#define WS 68            // fp16 weight row stride: word-stride 34=2*odd -> b64 conflict-free

typedef __attribute__((ext_vector_type(8))) _Float16 half8;
typedef __attribute__((ext_vector_type(4))) _Float16 half4f;
typedef __attribute__((ext_vector_type(2))) _Float16 half2f;

#if __has_builtin(__builtin_amdgcn_fdot2)
__device__ __forceinline__ float fdot2f(half2f a, half2f b, float c) {
  return __builtin_amdgcn_fdot2(a, b, c, false);
}
#else
__device__ __forceinline__ float fdot2f(half2f a, half2f b, float c) {
  return fmaf((float)a[0], (float)b[0], fmaf((float)a[1], (float)b[1], c));
}
#endif

__device__ __forceinline__ float fast_sig(float s) {
  return 1.f / (1.f + __expf(-s));
}
__device__ __forceinline__ float fast_tanh(float s) {
  float e = __expf(-2.f * fabsf(s));
  float t = 1.f - 2.f * e / (1.f + e);
  return copysignf(t, s);
}

// ---------------- Kernel 0: build padded ELL (colh = col*HID) ---------------
__global__ __launch_bounds__(256) void k_build_ell(
    const float* __restrict__ L, float* __restrict__ ell_val,
    _Float16* __restrict__ ell_valh, int* __restrict__ ell_colh,
    int* __restrict__ ell_cnt) {
  int wave = (blockIdx.x * blockDim.x + threadIdx.x) >> 6;
  int lane = threadIdx.x & 63;
  if (wave >= N_NODES) return;
  const float* row = L + (size_t)wave * N_NODES;
  int base = 0;
  for (int c = 0; c < N_NODES / 64; ++c) {
    int col = c * 64 + lane;
    float v = row[col];
    bool nz = (v != 0.0f);
    unsigned long long mask = __ballot(nz);
    int before = __popcll(mask & ((1ull << lane) - 1ull));
    if (nz) {
      int slot = base + before;
      if (slot < CAP) {
        ell_colh[wave * CAP + slot] = col * HID;
        ell_val[wave * CAP + slot] = v;
        ell_valh[wave * CAP + slot] = (_Float16)v;
      }
    }
    base += __popcll(mask);
  }
  if (base > CAP) base = CAP;
  int pad = (base + 7) & ~7;
  if (pad > CAP) pad = CAP;
  for (int s = base + lane; s < pad; s += 64) {
    ell_colh[wave * CAP + s] = 0;
    ell_val[wave * CAP + s] = 0.f;
    ell_valh[wave * CAP + s] = (_Float16)0.f;
  }
  if (lane == 0) ell_cnt[wave] = pad;
}

// ---------------- Transpose x[b][t][n] -> xT[n][tb],  tb = t*8 + b ----------
__global__ __launch_bounds__(256) void k_xt(const float* __restrict__ x,
                                            float* __restrict__ xT) {
  __shared__ float s[32][65];
  int n0  = (blockIdx.x & 63) * 32;
  int tb0 = (blockIdx.x >> 6) * 64;
  for (int idx = threadIdx.x; idx < 32 * 64; idx += 256) {
    int ln = idx & 31, ltb = idx >> 5;
    int tb = tb0 + ltb; int b = tb & 7, t = tb >> 3;
    s[ln][ltb] = x[((size_t)b * SEQ + t) * N_NODES + n0 + ln];
  }
  __syncthreads();
  for (int idx = threadIdx.x; idx < 32 * 64; idx += 256) {
    int ln = idx >> 6, ltb = idx & 63;
    xT[(size_t)(n0 + ln) * TB + tb0 + ltb] = s[ln][ltb];
  }
}

// ---------------- LxT[m][tb] = sum_n L[m,n] * xT[n][tb] ---------------------
__global__ __launch_bounds__(512) void k_spmm_x(
    const float* __restrict__ xT, const float* __restrict__ ell_val,
    const int* __restrict__ ell_colh, const int* __restrict__ ell_cnt,
    float* __restrict__ LxT) {
  int m = (blockIdx.x * blockDim.x + threadIdx.x) >> 6;
  int lane = threadIdx.x & 63;
  if (m >= N_NODES) return;
  const int* cp = ell_colh + m * CAP;
  const float* vp = ell_val + m * CAP;
  int cnt = ell_cnt[m];
  float4 acc = {0.f, 0.f, 0.f, 0.f};
  for (int k = 0; k < cnt; k += 4) {
    int4 c = *(const int4*)(cp + k);
    float4 v = *(const float4*)(vp + k);
    float4 xa = *(const float4*)&xT[(size_t)c.x * 4 + lane * 4];
    float4 xb = *(const float4*)&xT[(size_t)c.y * 4 + lane * 4];
    float4 xc = *(const float4*)&xT[(size_t)c.z * 4 + lane * 4];
    float4 xd = *(const float4*)&xT[(size_t)c.w * 4 + lane * 4];
    acc.x = fmaf(v.x, xa.x, acc.x); acc.y = fmaf(v.x, xa.y, acc.y);
    acc.z = fmaf(v.x, xa.z, acc.z); acc.w = fmaf(v.x, xa.w, acc.w);
    acc.x = fmaf(v.y, xb.x, acc.x); acc.y = fmaf(v.y, xb.y, acc.y);
    acc.z = fmaf(v.y, xb.z, acc.z); acc.w = fmaf(v.y, xb.w, acc.w);
    acc.x = fmaf(v.z, xc.x, acc.x); acc.y = fmaf(v.z, xc.y, acc.y);
    acc.z = fmaf(v.z, xc.z, acc.z); acc.w = fmaf(v.z, xc.w, acc.w);
    acc.x = fmaf(v.w, xd.x, acc.x); acc.y = fmaf(v.w, xd.y, acc.y);
    acc.z = fmaf(v.w, xd.z, acc.z); acc.w = fmaf(v.w, xd.w, acc.w);
  }
  *(float4*)&LxT[(size_t)m * TB + lane * 4] = acc;
}

// ---------------- Kernel 1: gates (fp16 gather + dot2 dense) ----------------
// Wave = row m, all 8 batches. Gather: 1 dwordx4 + 4 v_pk_fma_f16 per nnz.
// Dense: fp16 W rows (stride WS=68 halves -> conflict-free ds_read_b64),
// v_dot2_f32_f16 accumulation, diff broadcast via 16B same-address reads.
__global__ __launch_bounds__(256, 4) void k_gates(
    const half8* __restrict__ statepk, const float* __restrict__ LxT,
    const _Float16* __restrict__ ell_valh, const int* __restrict__ ell_colh,
    const int* __restrict__ ell_cnt, const float* __restrict__ Wg,
    const float* __restrict__ bg, half8* __restrict__ rspk,
    half8* __restrict__ upk, int t) {
  __shared__ _Float16 sWg[128 * WS];
  __shared__ float sWgx[128], sbg[128];
  __shared__ _Float16 sdiff[4][8][64];
  for (int idx = threadIdx.x; idx < 128 * 64; idx += 256) {
    int o = idx >> 6, h = idx & 63;
    sWg[o * WS + h] = (_Float16)Wg[o * 65 + 1 + h];
  }
  if (threadIdx.x < 128) {
    sWgx[threadIdx.x] = Wg[threadIdx.x * 65];
    sbg[threadIdx.x]  = bg[threadIdx.x];
  }
  __syncthreads();
  int wv = threadIdx.x >> 6, lane = threadIdx.x & 63;
  int m = blockIdx.x * 4 + wv;
  const half8* pk = statepk + lane;
  const int* cp = ell_colh + m * CAP;
  const _Float16* vp = ell_valh + m * CAP;
  int cnt = ell_cnt[m];
  half2f a01 = {0, 0}, a23 = {0, 0}, a45 = {0, 0}, a67 = {0, 0};
  for (int k = 0; k < cnt; k += 8) {
    int4 ca = *(const int4*)(cp + k);
    int4 cb = *(const int4*)(cp + k + 4);
    half8 vv = *(const half8*)(vp + k);
#define GATH(C, V) { half8 hv = pk[C]; \
    const half2f* h2 = (const half2f*)&hv; \
    half2f vs = {V, V}; \
    a01 += vs * h2[0]; a23 += vs * h2[1]; \
    a45 += vs * h2[2]; a67 += vs * h2[3]; }
    GATH(ca.x, vv[0]) GATH(ca.y, vv[1]) GATH(ca.z, vv[2]) GATH(ca.w, vv[3])
    GATH(cb.x, vv[4]) GATH(cb.y, vv[5]) GATH(cb.z, vv[6]) GATH(cb.w, vv[7])
#undef GATH
  }
  sdiff[wv][0][lane] = a01[0]; sdiff[wv][1][lane] = a01[1];
  sdiff[wv][2][lane] = a23[0]; sdiff[wv][3][lane] = a23[1];
  sdiff[wv][4][lane] = a45[0]; sdiff[wv][5][lane] = a45[1];
  sdiff[wv][6][lane] = a67[0]; sdiff[wv][7][lane] = a67[1];
  // wave-private sdiff rows: compiler orders via lgkmcnt, no barrier needed
  float4 LxLo = *(const float4*)&LxT[(size_t)m * TB + t * BATCH];
  float4 LxHi = *(const float4*)&LxT[(size_t)m * TB + t * BATCH + 4];
  float Lx8[8] = {LxLo.x, LxLo.y, LxLo.z, LxLo.w,
                  LxHi.x, LxHi.y, LxHi.z, LxHi.w};
  int o0 = lane, o1 = lane + 64;
  float wx0 = sWgx[o0], bg0 = sbg[o0];
  float wx1 = sWgx[o1], bg1 = sbg[o1];
  float s0[8], s1[8];
  #pragma unroll
  for (int b = 0; b < 8; ++b) {
    s0[b] = fmaf(Lx8[b], wx0, bg0);
    s1[b] = fmaf(Lx8[b], wx1, bg1);
  }
  const _Float16* w0p = sWg + o0 * WS;
  const _Float16* w1p = sWg + o1 * WS;
  #pragma unroll
  for (int J = 0; J < 8; ++J) {
    half4f w0a = *(const half4f*)(w0p + J * 8);
    half4f w0b = *(const half4f*)(w0p + J * 8 + 4);
    half4f w1a = *(const half4f*)(w1p + J * 8);
    half4f w1b = *(const half4f*)(w1p + J * 8 + 4);
    const half2f* w0l = (const half2f*)&w0a; const half2f* w0h = (const half2f*)&w0b;
    const half2f* w1l = (const half2f*)&w1a; const half2f* w1h = (const half2f*)&w1b;
    #pragma unroll
    for (int b = 0; b < 8; ++b) {
      half8 dv = *(const half8*)&sdiff[wv][b][J * 8];   // broadcast, same addr
      const half2f* d2 = (const half2f*)&dv;
      s0[b] = fdot2f(d2[0], w0l[0], fdot2f(d2[1], w0l[1],
              fdot2f(d2[2], w0h[0], fdot2f(d2[3], w0h[1], s0[b]))));
      s1[b] = fdot2f(d2[0], w1l[0], fdot2f(d2[1], w1l[1],
              fdot2f(d2[2], w1h[0], fdot2f(d2[3], w1h[1], s1[b]))));
    }
  }
  if (m < N_NODES / 2) {
    // r-half: flat gate idx == flat state idx (rep0 -> node 2m, rep1 -> 2m+1)
    half8 sp0 = pk[m * 128];
    half8 sp1 = pk[m * 128 + 64];
    half8 r0, r1;
    #pragma unroll
    for (int b = 0; b < 8; ++b) {
      r0[b] = (_Float16)(fast_sig(s0[b]) * (float)sp0[b]);
      r1[b] = (_Float16)(fast_sig(s1[b]) * (float)sp1[b]);
    }
    half8* rp = rspk + lane;
    rp[m * 128] = r0;
    rp[m * 128 + 64] = r1;
  } else {
    int mm = m - N_NODES / 2;
    half8 u0, u1;
    #pragma unroll
    for (int b = 0; b < 8; ++b) {
      u0[b] = (_Float16)fast_sig(s0[b]);
      u1[b] = (_Float16)fast_sig(s1[b]);
    }
    half8* up2 = upk + lane;
    up2[mm * 128] = u0;
    up2[mm * 128 + 64] = u1;
  }
}

// ---------------- Kernel 2: cand + GRU update (gathers rspk) ----------------
__global__ __launch_bounds__(256, 4) void k_cand(
    const half8* __restrict__ statepk, const float* __restrict__ LxT,
    const _Float16* __restrict__ ell_valh, const int* __restrict__ ell_colh,
    const int* __restrict__ ell_cnt, const float* __restrict__ Wc,
    const float* __restrict__ bc, const half8* __restrict__ rspk,
    const half8* __restrict__ upk, half8* __restrict__ statepk_next,
    float* __restrict__ out, int t) {
  __shared__ _Float16 sWc[64 * WS];
  __shared__ float sWcx[64], sbc[64];
  __shared__ _Float16 sdiff[4][8][64];
  for (int idx = threadIdx.x; idx < 64 * 64; idx += 256) {
    int o = idx >> 6, h = idx & 63;
    sWc[o * WS + h] = (_Float16)Wc[o * 65 + 1 + h];
  }
  if (threadIdx.x < 64) {
    sWcx[threadIdx.x] = Wc[threadIdx.x * 65];
    sbc[threadIdx.x]  = bc[threadIdx.x];
  }
  __syncthreads();
  int wv = threadIdx.x >> 6, lane = threadIdx.x & 63;
  int m = blockIdx.x * 4 + wv;
  const half8* rk = rspk + lane;
  const int* cp = ell_colh + m * CAP;
  const _Float16* vp = ell_valh + m * CAP;
  int cnt = ell_cnt[m];
  half2f a01 = {0, 0}, a23 = {0, 0}, a45 = {0, 0}, a67 = {0, 0};
  for (int k = 0; k < cnt; k += 8) {
    int4 ca = *(const int4*)(cp + k);
    int4 cb = *(const int4*)(cp + k + 4);
    half8 vv = *(const half8*)(vp + k);
#define GATH(C, V) { half8 hv = rk[C]; \
    const half2f* h2 = (const half2f*)&hv; \
    half2f vs = {V, V}; \
    a01 += vs * h2[0]; a23 += vs * h2[1]; \
    a45 += vs * h2[2]; a67 += vs * h2[3]; }
    GATH(ca.x, vv[0]) GATH(ca.y, vv[1]) GATH(ca.z, vv[2]) GATH(ca.w, vv[3])
    GATH(cb.x, vv[4]) GATH(cb.y, vv[5]) GATH(cb.z, vv[6]) GATH(cb.w, vv[7])
#undef GATH
  }
  sdiff[wv][0][lane] = a01[0]; sdiff[wv][1][lane] = a01[1];
  sdiff[wv][2][lane] = a23[0]; sdiff[wv][3][lane] = a23[1];
  sdiff[wv][4][lane] = a45[0]; sdiff[wv][5][lane] = a45[1];
  sdiff[wv][6][lane] = a67[0]; sdiff[wv][7][lane] = a67[1];
  float4 LxLo = *(const float4*)&LxT[(size_t)m * TB + t * BATCH];
  float4 LxHi = *(const float4*)&LxT[(size_t)m * TB + t * BATCH + 4];
  float Lx8[8] = {LxLo.x, LxLo.y, LxLo.z, LxLo.w,
                  LxHi.x, LxHi.y, LxHi.z, LxHi.w};
  float wxc = sWcx[lane], bbc = sbc[lane];
  float s[8];
  #pragma unroll
  for (int b = 0; b < 8; ++b) s[b] = fmaf(Lx8[b], wxc, bbc);
  const _Float16* wp = sWc + lane * WS;
  #pragma unroll
  for (int J = 0; J < 8; ++J) {
    half4f wa = *(const half4f*)(wp + J * 8);
    half4f wb = *(const half4f*)(wp + J * 8 + 4);
    const half2f* wl = (const half2f*)&wa; const half2f* wh = (const half2f*)&wb;
    #pragma unroll
    for (int b = 0; b < 8; ++b) {
      half8 dv = *(const half8*)&sdiff[wv][b][J * 8];
      const half2f* d2 = (const half2f*)&dv;
      s[b] = fdot2f(d2[0], wl[0], fdot2f(d2[1], wl[1],
             fdot2f(d2[2], wh[0], fdot2f(d2[3], wh[1], s[b]))));
    }
  }
  half8 hp = (statepk + lane)[m * 64];
  half8 uu = (upk + lane)[m * 64];
  half8 np;
  float* op = out + (size_t)t * BATCH * NH + m * HID + lane;
  #pragma unroll
  for (int b = 0; b < 8; ++b) {
    float u = (float)uu[b];
    float nh = u * (float)hp[b] + (1.f - u) * fast_tanh(s[b]);
    np[b] = (_Float16)nh;
    op[(size_t)b * NH] = nh;
  }
  (statepk_next + lane)[m * 64] = np;
}

extern "C" void kernel_launch(void* const* d_in, const int* in_sizes, int n_in,
                              void* d_out, int out_size, void* d_ws, size_t ws_size,
                              hipStream_t stream) {
  const float* x  = (const float*)d_in[0];
  const float* L  = (const float*)d_in[1];
  const float* Wg = (const float*)d_in[2];
  const float* bg = (const float*)d_in[3];
  const float* Wc = (const float*)d_in[4];
  const float* bc = (const float*)d_in[5];
  float* out = (float*)d_out;
  float* ws = (float*)d_ws;

  float*    ell_val  = ws;                                      // N*CAP f32
  int*      ell_colh = (int*)(ws + (size_t)N_NODES * CAP);      // N*CAP i32
  _Float16* ell_valh = (_Float16*)(ws + (size_t)2 * N_NODES * CAP); // N*CAP f16
  int*      ell_cnt  = (int*)(ws + (size_t)2 * N_NODES * CAP + N_NODES * CAP / 2); // N
  float* xT  = ws + (size_t)2 * N_NODES * CAP + N_NODES * CAP / 2 + N_NODES;
  float* LxT = xT + (size_t)N_NODES * TB;
  float* fend = LxT + (size_t)N_NODES * TB;
  half8* stA  = (half8*)fend;                                   // N*64 half8 = 2MB
  half8* stB  = stA + (size_t)N_NODES * HID;
  half8* rspk = stB + (size_t)N_NODES * HID;
  half8* upk  = rspk + (size_t)N_NODES * HID;

  k_build_ell<<<N_NODES / 4, 256, 0, stream>>>(L, ell_val, ell_valh, ell_colh,
                                               ell_cnt);
  k_xt<<<256, 256, 0, stream>>>(x, xT);
  k_spmm_x<<<N_NODES / 8, 512, 0, stream>>>(xT, ell_val, ell_colh, ell_cnt, LxT);
  hipMemsetAsync(stA, 0, (size_t)N_NODES * HID * sizeof(half8), stream);

  half8* cur = stA;
  half8* nxt = stB;
  for (int t = 0; t < SEQ; ++t) {
    k_gates<<<N_NODES / 4, 256, 0, stream>>>(cur, LxT, ell_valh, ell_colh,
                                             ell_cnt, Wg, bg, rspk, upk, t);
    k_cand<<<N_NODES / 4, 256, 0, stream>>>(cur, LxT, ell_valh, ell_colh,
                                            ell_cnt, Wc, bc, rspk, upk, nxt,
                                            out, t);
    half8* tmp = cur; cur = nxt; nxt = tmp;
  }
}

// Round 9
// 712.724 us; speedup vs baseline: 4.2184x; 1.1429x over previous
//
#include <hip/hip_runtime.h>
#include <math.h>

#define N_NODES 2048
#define HID 64
#define BATCH 8
#define SEQ 32
#define CAP 64           // ELL slots per row (nnz/row ~33, max ~55, padded x8)
#define TB 256           // SEQ*BATCH
#define NH (N_NODES*HID) // 131072 per batch
#define WS2 72           // fp16 LDS row stride (halves): 16B-aligned, ~2-way banks
#define CSA 133          // f32 C-tile stride (words), gcd(133%32=5,32)=1 -> conflict-free
#define CSB 69           // f32 C-tile stride for cand (69%32=5)

typedef __attribute__((ext_vector_type(8))) _Float16 half8;
typedef __attribute__((ext_vector_type(2))) _Float16 half2f;
typedef __attribute__((ext_vector_type(8))) _Float16 f16x8;
typedef __attribute__((ext_vector_type(4))) float f32x4;

__device__ __forceinline__ float fast_sig(float s) {
  return 1.f / (1.f + __expf(-s));
}
__device__ __forceinline__ float fast_tanh(float s) {
  float e = __expf(-2.f * fabsf(s));
  float t = 1.f - 2.f * e / (1.f + e);
  return copysignf(t, s);
}

// ---------------- Kernel 0: build padded ELL (colh = col*HID) ---------------
__global__ __launch_bounds__(256) void k_build_ell(
    const float* __restrict__ L, float* __restrict__ ell_val,
    _Float16* __restrict__ ell_valh, int* __restrict__ ell_colh,
    int* __restrict__ ell_cnt) {
  int wave = (blockIdx.x * blockDim.x + threadIdx.x) >> 6;
  int lane = threadIdx.x & 63;
  if (wave >= N_NODES) return;
  const float* row = L + (size_t)wave * N_NODES;
  int base = 0;
  for (int c = 0; c < N_NODES / 64; ++c) {
    int col = c * 64 + lane;
    float v = row[col];
    bool nz = (v != 0.0f);
    unsigned long long mask = __ballot(nz);
    int before = __popcll(mask & ((1ull << lane) - 1ull));
    if (nz) {
      int slot = base + before;
      if (slot < CAP) {
        ell_colh[wave * CAP + slot] = col * HID;
        ell_val[wave * CAP + slot] = v;
        ell_valh[wave * CAP + slot] = (_Float16)v;
      }
    }
    base += __popcll(mask);
  }
  if (base > CAP) base = CAP;
  int pad = (base + 7) & ~7;
  if (pad > CAP) pad = CAP;
  for (int s = base + lane; s < pad; s += 64) {
    ell_colh[wave * CAP + s] = 0;
    ell_val[wave * CAP + s] = 0.f;
    ell_valh[wave * CAP + s] = (_Float16)0.f;
  }
  if (lane == 0) ell_cnt[wave] = pad;
}

// ---------------- Transpose x[b][t][n] -> xT[n][tb],  tb = t*8 + b ----------
__global__ __launch_bounds__(256) void k_xt(const float* __restrict__ x,
                                            float* __restrict__ xT) {
  __shared__ float s[32][65];
  int n0  = (blockIdx.x & 63) * 32;
  int tb0 = (blockIdx.x >> 6) * 64;
  for (int idx = threadIdx.x; idx < 32 * 64; idx += 256) {
    int ln = idx & 31, ltb = idx >> 5;
    int tb = tb0 + ltb; int b = tb & 7, t = tb >> 3;
    s[ln][ltb] = x[((size_t)b * SEQ + t) * N_NODES + n0 + ln];
  }
  __syncthreads();
  for (int idx = threadIdx.x; idx < 32 * 64; idx += 256) {
    int ln = idx >> 6, ltb = idx & 63;
    xT[(size_t)(n0 + ln) * TB + tb0 + ltb] = s[ln][ltb];
  }
}

// ---------------- LxT[m][tb] = sum_n L[m,n] * xT[n][tb] ---------------------
__global__ __launch_bounds__(512) void k_spmm_x(
    const float* __restrict__ xT, const float* __restrict__ ell_val,
    const int* __restrict__ ell_colh, const int* __restrict__ ell_cnt,
    float* __restrict__ LxT) {
  int m = (blockIdx.x * blockDim.x + threadIdx.x) >> 6;
  int lane = threadIdx.x & 63;
  if (m >= N_NODES) return;
  const int* cp = ell_colh + m * CAP;
  const float* vp = ell_val + m * CAP;
  int cnt = ell_cnt[m];
  float4 acc = {0.f, 0.f, 0.f, 0.f};
  for (int k = 0; k < cnt; k += 4) {
    int4 c = *(const int4*)(cp + k);
    float4 v = *(const float4*)(vp + k);
    float4 xa = *(const float4*)&xT[(size_t)c.x * 4 + lane * 4];
    float4 xb = *(const float4*)&xT[(size_t)c.y * 4 + lane * 4];
    float4 xc = *(const float4*)&xT[(size_t)c.z * 4 + lane * 4];
    float4 xd = *(const float4*)&xT[(size_t)c.w * 4 + lane * 4];
    acc.x = fmaf(v.x, xa.x, acc.x); acc.y = fmaf(v.x, xa.y, acc.y);
    acc.z = fmaf(v.x, xa.z, acc.z); acc.w = fmaf(v.x, xa.w, acc.w);
    acc.x = fmaf(v.y, xb.x, acc.x); acc.y = fmaf(v.y, xb.y, acc.y);
    acc.z = fmaf(v.y, xb.z, acc.z); acc.w = fmaf(v.y, xb.w, acc.w);
    acc.x = fmaf(v.z, xc.x, acc.x); acc.y = fmaf(v.z, xc.y, acc.y);
    acc.z = fmaf(v.z, xc.z, acc.z); acc.w = fmaf(v.z, xc.w, acc.w);
    acc.x = fmaf(v.w, xd.x, acc.x); acc.y = fmaf(v.w, xd.y, acc.y);
    acc.z = fmaf(v.w, xd.z, acc.z); acc.w = fmaf(v.w, xd.w, acc.w);
  }
  *(float4*)&LxT[(size_t)m * TB + lane * 4] = acc;
}

// ---------------- Kernel 1: gates (fp16 gather + MFMA dense) ----------------
// Block = 4 waves = 4 nodes x 8 batches. Gather -> sdiff[32 rows][72] fp16
// (row = wv*8+b). Dense: C[o][r] = Wg(128x64) . diff^T via mfma 16x16x32_f16,
// 16 tiles, K=64 (2 steps). C staged f32 in sC[r][133]; epilogue adds
// Lx*wx+bias, applies sigmoid, keeps flat-split r/u semantics.
__global__ __launch_bounds__(256, 4) void k_gates(
    const half8* __restrict__ statepk, const float* __restrict__ LxT,
    const _Float16* __restrict__ ell_valh, const int* __restrict__ ell_colh,
    const int* __restrict__ ell_cnt, const float* __restrict__ Wg,
    const float* __restrict__ bg, half8* __restrict__ rspk,
    half8* __restrict__ upk, int t) {
  __shared__ __align__(16) _Float16 sWh[128 * WS2];
  __shared__ float sWgx[128], sbg[128];
  __shared__ __align__(16) _Float16 sdiff[32 * WS2];
  __shared__ float sC[32 * CSA];
  for (int idx = threadIdx.x; idx < 128 * 64; idx += 256) {
    int o = idx >> 6, h = idx & 63;
    sWh[o * WS2 + h] = (_Float16)Wg[o * 65 + 1 + h];
  }
  if (threadIdx.x < 128) {
    sWgx[threadIdx.x] = Wg[threadIdx.x * 65];
    sbg[threadIdx.x]  = bg[threadIdx.x];
  }
  int wv = threadIdx.x >> 6, lane = threadIdx.x & 63;
  int m = blockIdx.x * 4 + wv;
  const half8* pk = statepk + lane;
  const int* cp = ell_colh + m * CAP;
  const _Float16* vp = ell_valh + m * CAP;
  int cnt = ell_cnt[m];
  half2f a01 = {0, 0}, a23 = {0, 0}, a45 = {0, 0}, a67 = {0, 0};
  for (int k = 0; k < cnt; k += 8) {
    int4 ca = *(const int4*)(cp + k);
    int4 cb = *(const int4*)(cp + k + 4);
    half8 vv = *(const half8*)(vp + k);
#define GATH(C, V) { half8 hv = pk[C]; \
    const half2f* h2 = (const half2f*)&hv; \
    half2f vs = {V, V}; \
    a01 += vs * h2[0]; a23 += vs * h2[1]; \
    a45 += vs * h2[2]; a67 += vs * h2[3]; }
    GATH(ca.x, vv[0]) GATH(ca.y, vv[1]) GATH(ca.z, vv[2]) GATH(ca.w, vv[3])
    GATH(cb.x, vv[4]) GATH(cb.y, vv[5]) GATH(cb.z, vv[6]) GATH(cb.w, vv[7])
#undef GATH
  }
  {
    int r0 = wv * 8;
    sdiff[(r0 + 0) * WS2 + lane] = a01[0];
    sdiff[(r0 + 1) * WS2 + lane] = a01[1];
    sdiff[(r0 + 2) * WS2 + lane] = a23[0];
    sdiff[(r0 + 3) * WS2 + lane] = a23[1];
    sdiff[(r0 + 4) * WS2 + lane] = a45[0];
    sdiff[(r0 + 5) * WS2 + lane] = a45[1];
    sdiff[(r0 + 6) * WS2 + lane] = a67[0];
    sdiff[(r0 + 7) * WS2 + lane] = a67[1];
  }
  __syncthreads();
  int l15 = lane & 15, lq = lane >> 4;
  #pragma unroll
  for (int tt = 0; tt < 4; ++tt) {
    int tid = wv * 4 + tt;
    int ot = tid >> 1, rt = tid & 1;
    f32x4 acc = {0.f, 0.f, 0.f, 0.f};
    #pragma unroll
    for (int s = 0; s < 2; ++s) {
      f16x8 af = *(const f16x8*)&sWh[(ot * 16 + l15) * WS2 + s * 32 + lq * 8];
      f16x8 bf = *(const f16x8*)&sdiff[(rt * 16 + l15) * WS2 + s * 32 + lq * 8];
      acc = __builtin_amdgcn_mfma_f32_16x16x32_f16(af, bf, acc, 0, 0, 0);
    }
    int R = rt * 16 + l15;
    int O = ot * 16 + lq * 4;
    sC[R * CSA + O + 0] = acc[0];
    sC[R * CSA + O + 1] = acc[1];
    sC[R * CSA + O + 2] = acc[2];
    sC[R * CSA + O + 3] = acc[3];
  }
  __syncthreads();
  float4 LxLo = *(const float4*)&LxT[(size_t)m * TB + t * BATCH];
  float4 LxHi = *(const float4*)&LxT[(size_t)m * TB + t * BATCH + 4];
  float Lx8[8] = {LxLo.x, LxLo.y, LxLo.z, LxLo.w,
                  LxHi.x, LxHi.y, LxHi.z, LxHi.w};
  int o0 = lane, o1 = lane + 64;
  float wx0 = sWgx[o0], bg0 = sbg[o0];
  float wx1 = sWgx[o1], bg1 = sbg[o1];
  float s0[8], s1[8];
  #pragma unroll
  for (int b = 0; b < 8; ++b) {
    int R = wv * 8 + b;
    s0[b] = sC[R * CSA + o0] + fmaf(Lx8[b], wx0, bg0);
    s1[b] = sC[R * CSA + o1] + fmaf(Lx8[b], wx1, bg1);
  }
  if (m < N_NODES / 2) {
    // r-half: flat gate idx == flat state idx (rep0 -> node 2m, rep1 -> 2m+1)
    half8 sp0 = pk[m * 128];
    half8 sp1 = pk[m * 128 + 64];
    half8 r0, r1;
    #pragma unroll
    for (int b = 0; b < 8; ++b) {
      r0[b] = (_Float16)(fast_sig(s0[b]) * (float)sp0[b]);
      r1[b] = (_Float16)(fast_sig(s1[b]) * (float)sp1[b]);
    }
    half8* rp = rspk + lane;
    rp[m * 128] = r0;
    rp[m * 128 + 64] = r1;
  } else {
    int mm = m - N_NODES / 2;
    half8 u0, u1;
    #pragma unroll
    for (int b = 0; b < 8; ++b) {
      u0[b] = (_Float16)fast_sig(s0[b]);
      u1[b] = (_Float16)fast_sig(s1[b]);
    }
    half8* up2 = upk + lane;
    up2[mm * 128] = u0;
    up2[mm * 128 + 64] = u1;
  }
}

// ---------------- Kernel 2: cand + GRU update (gather rspk + MFMA dense) ----
__global__ __launch_bounds__(256, 4) void k_cand(
    const half8* __restrict__ statepk, const float* __restrict__ LxT,
    const _Float16* __restrict__ ell_valh, const int* __restrict__ ell_colh,
    const int* __restrict__ ell_cnt, const float* __restrict__ Wc,
    const float* __restrict__ bc, const half8* __restrict__ rspk,
    const half8* __restrict__ upk, half8* __restrict__ statepk_next,
    float* __restrict__ out, int t) {
  __shared__ __align__(16) _Float16 sWh[64 * WS2];
  __shared__ float sWcx[64], sbc[64];
  __shared__ __align__(16) _Float16 sdiff[32 * WS2];
  __shared__ float sC[32 * CSB];
  for (int idx = threadIdx.x; idx < 64 * 64; idx += 256) {
    int o = idx >> 6, h = idx & 63;
    sWh[o * WS2 + h] = (_Float16)Wc[o * 65 + 1 + h];
  }
  if (threadIdx.x < 64) {
    sWcx[threadIdx.x] = Wc[threadIdx.x * 65];
    sbc[threadIdx.x]  = bc[threadIdx.x];
  }
  int wv = threadIdx.x >> 6, lane = threadIdx.x & 63;
  int m = blockIdx.x * 4 + wv;
  const half8* rk = rspk + lane;
  const int* cp = ell_colh + m * CAP;
  const _Float16* vp = ell_valh + m * CAP;
  int cnt = ell_cnt[m];
  half2f a01 = {0, 0}, a23 = {0, 0}, a45 = {0, 0}, a67 = {0, 0};
  for (int k = 0; k < cnt; k += 8) {
    int4 ca = *(const int4*)(cp + k);
    int4 cb = *(const int4*)(cp + k + 4);
    half8 vv = *(const half8*)(vp + k);
#define GATH(C, V) { half8 hv = rk[C]; \
    const half2f* h2 = (const half2f*)&hv; \
    half2f vs = {V, V}; \
    a01 += vs * h2[0]; a23 += vs * h2[1]; \
    a45 += vs * h2[2]; a67 += vs * h2[3]; }
    GATH(ca.x, vv[0]) GATH(ca.y, vv[1]) GATH(ca.z, vv[2]) GATH(ca.w, vv[3])
    GATH(cb.x, vv[4]) GATH(cb.y, vv[5]) GATH(cb.z, vv[6]) GATH(cb.w, vv[7])
#undef GATH
  }
  {
    int r0 = wv * 8;
    sdiff[(r0 + 0) * WS2 + lane] = a01[0];
    sdiff[(r0 + 1) * WS2 + lane] = a01[1];
    sdiff[(r0 + 2) * WS2 + lane] = a23[0];
    sdiff[(r0 + 3) * WS2 + lane] = a23[1];
    sdiff[(r0 + 4) * WS2 + lane] = a45[0];
    sdiff[(r0 + 5) * WS2 + lane] = a45[1];
    sdiff[(r0 + 6) * WS2 + lane] = a67[0];
    sdiff[(r0 + 7) * WS2 + lane] = a67[1];
  }
  __syncthreads();
  int l15 = lane & 15, lq = lane >> 4;
  #pragma unroll
  for (int tt = 0; tt < 2; ++tt) {
    int tid = wv * 2 + tt;
    int ot = tid >> 1, rt = tid & 1;
    f32x4 acc = {0.f, 0.f, 0.f, 0.f};
    #pragma unroll
    for (int s = 0; s < 2; ++s) {
      f16x8 af = *(const f16x8*)&sWh[(ot * 16 + l15) * WS2 + s * 32 + lq * 8];
      f16x8 bf = *(const f16x8*)&sdiff[(rt * 16 + l15) * WS2 + s * 32 + lq * 8];
      acc = __builtin_amdgcn_mfma_f32_16x16x32_f16(af, bf, acc, 0, 0, 0);
    }
    int R = rt * 16 + l15;
    int O = ot * 16 + lq * 4;
    sC[R * CSB + O + 0] = acc[0];
    sC[R * CSB + O + 1] = acc[1];
    sC[R * CSB + O + 2] = acc[2];
    sC[R * CSB + O + 3] = acc[3];
  }
  __syncthreads();
  float4 LxLo = *(const float4*)&LxT[(size_t)m * TB + t * BATCH];
  float4 LxHi = *(const float4*)&LxT[(size_t)m * TB + t * BATCH + 4];
  float Lx8[8] = {LxLo.x, LxLo.y, LxLo.z, LxLo.w,
                  LxHi.x, LxHi.y, LxHi.z, LxHi.w};
  float wxc = sWcx[lane], bbc = sbc[lane];
  float s[8];
  #pragma unroll
  for (int b = 0; b < 8; ++b) {
    int R = wv * 8 + b;
    s[b] = sC[R * CSB + lane] + fmaf(Lx8[b], wxc, bbc);
  }
  half8 hp = (statepk + lane)[m * 64];
  half8 uu = (upk + lane)[m * 64];
  half8 np;
  float* op = out + (size_t)t * BATCH * NH + m * HID + lane;
  #pragma unroll
  for (int b = 0; b < 8; ++b) {
    float u = (float)uu[b];
    float nh = u * (float)hp[b] + (1.f - u) * fast_tanh(s[b]);
    np[b] = (_Float16)nh;
    op[(size_t)b * NH] = nh;
  }
  (statepk_next + lane)[m * 64] = np;
}

extern "C" void kernel_launch(void* const* d_in, const int* in_sizes, int n_in,
                              void* d_out, int out_size, void* d_ws, size_t ws_size,
                              hipStream_t stream) {
  const float* x  = (const float*)d_in[0];
  const float* L  = (const float*)d_in[1];
  const float* Wg = (const float*)d_in[2];
  const float* bg = (const float*)d_in[3];
  const float* Wc = (const float*)d_in[4];
  const float* bc = (const float*)d_in[5];
  float* out = (float*)d_out;
  float* ws = (float*)d_ws;

  float*    ell_val  = ws;                                      // N*CAP f32
  int*      ell_colh = (int*)(ws + (size_t)N_NODES * CAP);      // N*CAP i32
  _Float16* ell_valh = (_Float16*)(ws + (size_t)2 * N_NODES * CAP); // N*CAP f16
  int*      ell_cnt  = (int*)(ws + (size_t)2 * N_NODES * CAP + N_NODES * CAP / 2); // N
  float* xT  = ws + (size_t)2 * N_NODES * CAP + N_NODES * CAP / 2 + N_NODES;
  float* LxT = xT + (size_t)N_NODES * TB;
  float* fend = LxT + (size_t)N_NODES * TB;
  half8* stA  = (half8*)fend;                                   // N*64 half8 = 2MB
  half8* stB  = stA + (size_t)N_NODES * HID;
  half8* rspk = stB + (size_t)N_NODES * HID;
  half8* upk  = rspk + (size_t)N_NODES * HID;

  k_build_ell<<<N_NODES / 4, 256, 0, stream>>>(L, ell_val, ell_valh, ell_colh,
                                               ell_cnt);
  k_xt<<<256, 256, 0, stream>>>(x, xT);
  k_spmm_x<<<N_NODES / 8, 512, 0, stream>>>(xT, ell_val, ell_colh, ell_cnt, LxT);
  hipMemsetAsync(stA, 0, (size_t)N_NODES * HID * sizeof(half8), stream);

  half8* cur = stA;
  half8* nxt = stB;
  for (int t = 0; t < SEQ; ++t) {
    k_gates<<<N_NODES / 4, 256, 0, stream>>>(cur, LxT, ell_valh, ell_colh,
                                             ell_cnt, Wg, bg, rspk, upk, t);
    k_cand<<<N_NODES / 4, 256, 0, stream>>>(cur, LxT, ell_valh, ell_colh,
                                            ell_cnt, Wc, bc, rspk, upk, nxt,
                                            out, t);
    half8* tmp = cur; cur = nxt; nxt = tmp;
  }
}

// Round 10
// 689.958 us; speedup vs baseline: 4.3576x; 1.0330x over previous
//
#include <hip/hip_runtime.h>
#include <math.h>

#define N_NODES 2048
#define HID 64
#define BATCH 8
#define SEQ 32
#define CAP 64           // ELL slots per row (nnz/row ~33, max ~55, padded x8)
#define TB 256           // SEQ*BATCH
#define NH (N_NODES*HID) // 131072 per batch
#define WS2 72           // fp16 LDS row stride (halves): 16B-aligned, even bank spread
#define CSA2 132         // f32 C stride (words): even->b128-aligned, 2-way read banks
#define CSB2 68

typedef __attribute__((ext_vector_type(8))) _Float16 half8;
typedef __attribute__((ext_vector_type(2))) _Float16 half2f;
typedef __attribute__((ext_vector_type(8))) _Float16 f16x8;
typedef __attribute__((ext_vector_type(4))) float f32x4;

__device__ __forceinline__ float fast_sig(float s) {
  return 1.f / (1.f + __expf(-s));
}
__device__ __forceinline__ float fast_tanh(float s) {
  float e = __expf(-2.f * fabsf(s));
  float t = 1.f - 2.f * e / (1.f + e);
  return copysignf(t, s);
}

// ---------------- Kernel 0: build padded ELL (colh = col*HID) ---------------
__global__ __launch_bounds__(256) void k_build_ell(
    const float* __restrict__ L, float* __restrict__ ell_val,
    _Float16* __restrict__ ell_valh, int* __restrict__ ell_colh,
    int* __restrict__ ell_cnt) {
  int wave = (blockIdx.x * blockDim.x + threadIdx.x) >> 6;
  int lane = threadIdx.x & 63;
  if (wave >= N_NODES) return;
  const float* row = L + (size_t)wave * N_NODES;
  int base = 0;
  for (int c = 0; c < N_NODES / 64; ++c) {
    int col = c * 64 + lane;
    float v = row[col];
    bool nz = (v != 0.0f);
    unsigned long long mask = __ballot(nz);
    int before = __popcll(mask & ((1ull << lane) - 1ull));
    if (nz) {
      int slot = base + before;
      if (slot < CAP) {
        ell_colh[wave * CAP + slot] = col * HID;
        ell_val[wave * CAP + slot] = v;
        ell_valh[wave * CAP + slot] = (_Float16)v;
      }
    }
    base += __popcll(mask);
  }
  if (base > CAP) base = CAP;
  int pad = (base + 7) & ~7;
  if (pad > CAP) pad = CAP;
  for (int s = base + lane; s < pad; s += 64) {
    ell_colh[wave * CAP + s] = 0;
    ell_val[wave * CAP + s] = 0.f;
    ell_valh[wave * CAP + s] = (_Float16)0.f;
  }
  if (lane == 0) ell_cnt[wave] = pad;
}

// ---------------- Prolog: pre-swizzled fp16 W images + wx arrays ------------
__global__ __launch_bounds__(256) void k_prep(
    const float* __restrict__ Wg, const float* __restrict__ Wc,
    _Float16* __restrict__ Wg16, _Float16* __restrict__ Wc16,
    float* __restrict__ wgx, float* __restrict__ wcx) {
  int tid = blockIdx.x * blockDim.x + threadIdx.x;
  int nthr = gridDim.x * blockDim.x;
  for (int i = tid; i < 128 * WS2; i += nthr) {
    int o = i / WS2, h = i % WS2;
    Wg16[i] = (h < 64) ? (_Float16)Wg[o * 65 + 1 + h] : (_Float16)0.f;
  }
  for (int i = tid; i < 64 * WS2; i += nthr) {
    int o = i / WS2, h = i % WS2;
    Wc16[i] = (h < 64) ? (_Float16)Wc[o * 65 + 1 + h] : (_Float16)0.f;
  }
  if (tid < 128) wgx[tid] = Wg[tid * 65];
  else if (tid < 192) wcx[tid - 128] = Wc[(tid - 128) * 65];
}

// ---------------- Transpose x[b][t][n] -> xT[n][tb],  tb = t*8 + b ----------
__global__ __launch_bounds__(256) void k_xt(const float* __restrict__ x,
                                            float* __restrict__ xT) {
  __shared__ float s[32][65];
  int n0  = (blockIdx.x & 63) * 32;
  int tb0 = (blockIdx.x >> 6) * 64;
  for (int idx = threadIdx.x; idx < 32 * 64; idx += 256) {
    int ln = idx & 31, ltb = idx >> 5;
    int tb = tb0 + ltb; int b = tb & 7, t = tb >> 3;
    s[ln][ltb] = x[((size_t)b * SEQ + t) * N_NODES + n0 + ln];
  }
  __syncthreads();
  for (int idx = threadIdx.x; idx < 32 * 64; idx += 256) {
    int ln = idx >> 6, ltb = idx & 63;
    xT[(size_t)(n0 + ln) * TB + tb0 + ltb] = s[ln][ltb];
  }
}

// ---------------- LxT[m][tb] = sum_n L[m,n] * xT[n][tb] ---------------------
__global__ __launch_bounds__(512) void k_spmm_x(
    const float* __restrict__ xT, const float* __restrict__ ell_val,
    const int* __restrict__ ell_colh, const int* __restrict__ ell_cnt,
    float* __restrict__ LxT) {
  int m = (blockIdx.x * blockDim.x + threadIdx.x) >> 6;
  int lane = threadIdx.x & 63;
  if (m >= N_NODES) return;
  const int* cp = ell_colh + m * CAP;
  const float* vp = ell_val + m * CAP;
  int cnt = ell_cnt[m];
  float4 acc = {0.f, 0.f, 0.f, 0.f};
  for (int k = 0; k < cnt; k += 4) {
    int4 c = *(const int4*)(cp + k);
    float4 v = *(const float4*)(vp + k);
    float4 xa = *(const float4*)&xT[(size_t)c.x * 4 + lane * 4];
    float4 xb = *(const float4*)&xT[(size_t)c.y * 4 + lane * 4];
    float4 xc = *(const float4*)&xT[(size_t)c.z * 4 + lane * 4];
    float4 xd = *(const float4*)&xT[(size_t)c.w * 4 + lane * 4];
    acc.x = fmaf(v.x, xa.x, acc.x); acc.y = fmaf(v.x, xa.y, acc.y);
    acc.z = fmaf(v.x, xa.z, acc.z); acc.w = fmaf(v.x, xa.w, acc.w);
    acc.x = fmaf(v.y, xb.x, acc.x); acc.y = fmaf(v.y, xb.y, acc.y);
    acc.z = fmaf(v.y, xb.z, acc.z); acc.w = fmaf(v.y, xb.w, acc.w);
    acc.x = fmaf(v.z, xc.x, acc.x); acc.y = fmaf(v.z, xc.y, acc.y);
    acc.z = fmaf(v.z, xc.z, acc.z); acc.w = fmaf(v.z, xc.w, acc.w);
    acc.x = fmaf(v.w, xd.x, acc.x); acc.y = fmaf(v.w, xd.y, acc.y);
    acc.z = fmaf(v.w, xd.z, acc.z); acc.w = fmaf(v.w, xd.w, acc.w);
  }
  *(float4*)&LxT[(size_t)m * TB + lane * 4] = acc;
}

// ---------------- Kernel 1: gates (fp16 gather + MFMA dense) ----------------
__global__ __launch_bounds__(256, 4) void k_gates(
    const half8* __restrict__ statepk, const float* __restrict__ LxT,
    const _Float16* __restrict__ ell_valh, const int* __restrict__ ell_colh,
    const int* __restrict__ ell_cnt, const _Float16* __restrict__ Wg16,
    const float* __restrict__ wgx, const float* __restrict__ bg,
    half8* __restrict__ rspk, half8* __restrict__ upk, int t) {
  __shared__ __align__(16) _Float16 sWh[128 * WS2];
  __shared__ __align__(16) _Float16 sdiff[32 * WS2];
  __shared__ __align__(16) float sC[32 * CSA2];
  for (int idx = threadIdx.x; idx < 128 * WS2 / 8; idx += 256)
    ((uint4*)sWh)[idx] = ((const uint4*)Wg16)[idx];
  int wv = threadIdx.x >> 6, lane = threadIdx.x & 63;
  int m = blockIdx.x * 4 + wv;
  const half8* pk = statepk + lane;
  const int* cp = ell_colh + m * CAP;
  const _Float16* vp = ell_valh + m * CAP;
  int cnt = ell_cnt[m];
  half2f a01 = {0, 0}, a23 = {0, 0}, a45 = {0, 0}, a67 = {0, 0};
  for (int k = 0; k < cnt; k += 8) {
    int4 ca = *(const int4*)(cp + k);
    int4 cb = *(const int4*)(cp + k + 4);
    half8 vv = *(const half8*)(vp + k);
#define GATH(C, V) { half8 hv = pk[C]; \
    const half2f* h2 = (const half2f*)&hv; \
    half2f vs = {V, V}; \
    a01 += vs * h2[0]; a23 += vs * h2[1]; \
    a45 += vs * h2[2]; a67 += vs * h2[3]; }
    GATH(ca.x, vv[0]) GATH(ca.y, vv[1]) GATH(ca.z, vv[2]) GATH(ca.w, vv[3])
    GATH(cb.x, vv[4]) GATH(cb.y, vv[5]) GATH(cb.z, vv[6]) GATH(cb.w, vv[7])
#undef GATH
  }
  {
    int r0 = wv * 8;
    sdiff[(r0 + 0) * WS2 + lane] = a01[0];
    sdiff[(r0 + 1) * WS2 + lane] = a01[1];
    sdiff[(r0 + 2) * WS2 + lane] = a23[0];
    sdiff[(r0 + 3) * WS2 + lane] = a23[1];
    sdiff[(r0 + 4) * WS2 + lane] = a45[0];
    sdiff[(r0 + 5) * WS2 + lane] = a45[1];
    sdiff[(r0 + 6) * WS2 + lane] = a67[0];
    sdiff[(r0 + 7) * WS2 + lane] = a67[1];
  }
  __syncthreads();
  int l15 = lane & 15, lq = lane >> 4;
  #pragma unroll
  for (int tt = 0; tt < 4; ++tt) {
    int tid = wv * 4 + tt;
    int ot = tid >> 1, rt = tid & 1;
    f32x4 acc = {0.f, 0.f, 0.f, 0.f};
    #pragma unroll
    for (int s = 0; s < 2; ++s) {
      f16x8 af = *(const f16x8*)&sWh[(ot * 16 + l15) * WS2 + s * 32 + lq * 8];
      f16x8 bf = *(const f16x8*)&sdiff[(rt * 16 + l15) * WS2 + s * 32 + lq * 8];
      acc = __builtin_amdgcn_mfma_f32_16x16x32_f16(af, bf, acc, 0, 0, 0);
    }
    int R = rt * 16 + l15;
    int O = ot * 16 + lq * 4;
    *(f32x4*)&sC[R * CSA2 + O] = acc;
  }
  __syncthreads();
  float4 LxLo = *(const float4*)&LxT[(size_t)m * TB + t * BATCH];
  float4 LxHi = *(const float4*)&LxT[(size_t)m * TB + t * BATCH + 4];
  float Lx8[8] = {LxLo.x, LxLo.y, LxLo.z, LxLo.w,
                  LxHi.x, LxHi.y, LxHi.z, LxHi.w};
  int o0 = lane, o1 = lane + 64;
  float wx0 = wgx[o0], bg0 = bg[o0];
  float wx1 = wgx[o1], bg1 = bg[o1];
  float s0[8], s1[8];
  #pragma unroll
  for (int b = 0; b < 8; ++b) {
    int R = wv * 8 + b;
    s0[b] = sC[R * CSA2 + o0] + fmaf(Lx8[b], wx0, bg0);
    s1[b] = sC[R * CSA2 + o1] + fmaf(Lx8[b], wx1, bg1);
  }
  if (m < N_NODES / 2) {
    // r-half: flat gate idx == flat state idx (rep0 -> node 2m, rep1 -> 2m+1)
    half8 sp0 = pk[m * 128];
    half8 sp1 = pk[m * 128 + 64];
    half8 r0, r1;
    #pragma unroll
    for (int b = 0; b < 8; ++b) {
      r0[b] = (_Float16)(fast_sig(s0[b]) * (float)sp0[b]);
      r1[b] = (_Float16)(fast_sig(s1[b]) * (float)sp1[b]);
    }
    half8* rp = rspk + lane;
    rp[m * 128] = r0;
    rp[m * 128 + 64] = r1;
  } else {
    int mm = m - N_NODES / 2;
    half8 u0, u1;
    #pragma unroll
    for (int b = 0; b < 8; ++b) {
      u0[b] = (_Float16)fast_sig(s0[b]);
      u1[b] = (_Float16)fast_sig(s1[b]);
    }
    half8* up2 = upk + lane;
    up2[mm * 128] = u0;
    up2[mm * 128 + 64] = u1;
  }
}

// ---------------- Kernel 2: cand + GRU update (gather rspk + MFMA dense) ----
__global__ __launch_bounds__(256, 4) void k_cand(
    const half8* __restrict__ statepk, const float* __restrict__ LxT,
    const _Float16* __restrict__ ell_valh, const int* __restrict__ ell_colh,
    const int* __restrict__ ell_cnt, const _Float16* __restrict__ Wc16,
    const float* __restrict__ wcx, const float* __restrict__ bc,
    const half8* __restrict__ rspk, const half8* __restrict__ upk,
    half8* __restrict__ statepk_next, float* __restrict__ out, int t) {
  __shared__ __align__(16) _Float16 sWh[64 * WS2];
  __shared__ __align__(16) _Float16 sdiff[32 * WS2];
  __shared__ __align__(16) float sC[32 * CSB2];
  for (int idx = threadIdx.x; idx < 64 * WS2 / 8; idx += 256)
    ((uint4*)sWh)[idx] = ((const uint4*)Wc16)[idx];
  int wv = threadIdx.x >> 6, lane = threadIdx.x & 63;
  int m = blockIdx.x * 4 + wv;
  const half8* rk = rspk + lane;
  const int* cp = ell_colh + m * CAP;
  const _Float16* vp = ell_valh + m * CAP;
  int cnt = ell_cnt[m];
  half2f a01 = {0, 0}, a23 = {0, 0}, a45 = {0, 0}, a67 = {0, 0};
  for (int k = 0; k < cnt; k += 8) {
    int4 ca = *(const int4*)(cp + k);
    int4 cb = *(const int4*)(cp + k + 4);
    half8 vv = *(const half8*)(vp + k);
#define GATH(C, V) { half8 hv = rk[C]; \
    const half2f* h2 = (const half2f*)&hv; \
    half2f vs = {V, V}; \
    a01 += vs * h2[0]; a23 += vs * h2[1]; \
    a45 += vs * h2[2]; a67 += vs * h2[3]; }
    GATH(ca.x, vv[0]) GATH(ca.y, vv[1]) GATH(ca.z, vv[2]) GATH(ca.w, vv[3])
    GATH(cb.x, vv[4]) GATH(cb.y, vv[5]) GATH(cb.z, vv[6]) GATH(cb.w, vv[7])
#undef GATH
  }
  {
    int r0 = wv * 8;
    sdiff[(r0 + 0) * WS2 + lane] = a01[0];
    sdiff[(r0 + 1) * WS2 + lane] = a01[1];
    sdiff[(r0 + 2) * WS2 + lane] = a23[0];
    sdiff[(r0 + 3) * WS2 + lane] = a23[1];
    sdiff[(r0 + 4) * WS2 + lane] = a45[0];
    sdiff[(r0 + 5) * WS2 + lane] = a45[1];
    sdiff[(r0 + 6) * WS2 + lane] = a67[0];
    sdiff[(r0 + 7) * WS2 + lane] = a67[1];
  }
  __syncthreads();
  int l15 = lane & 15, lq = lane >> 4;
  #pragma unroll
  for (int tt = 0; tt < 2; ++tt) {
    int tid = wv * 2 + tt;
    int ot = tid >> 1, rt = tid & 1;
    f32x4 acc = {0.f, 0.f, 0.f, 0.f};
    #pragma unroll
    for (int s = 0; s < 2; ++s) {
      f16x8 af = *(const f16x8*)&sWh[(ot * 16 + l15) * WS2 + s * 32 + lq * 8];
      f16x8 bf = *(const f16x8*)&sdiff[(rt * 16 + l15) * WS2 + s * 32 + lq * 8];
      acc = __builtin_amdgcn_mfma_f32_16x16x32_f16(af, bf, acc, 0, 0, 0);
    }
    int R = rt * 16 + l15;
    int O = ot * 16 + lq * 4;
    *(f32x4*)&sC[R * CSB2 + O] = acc;
  }
  __syncthreads();
  float4 LxLo = *(const float4*)&LxT[(size_t)m * TB + t * BATCH];
  float4 LxHi = *(const float4*)&LxT[(size_t)m * TB + t * BATCH + 4];
  float Lx8[8] = {LxLo.x, LxLo.y, LxLo.z, LxLo.w,
                  LxHi.x, LxHi.y, LxHi.z, LxHi.w};
  float wxc = wcx[lane], bbc = bc[lane];
  float s[8];
  #pragma unroll
  for (int b = 0; b < 8; ++b) {
    int R = wv * 8 + b;
    s[b] = sC[R * CSB2 + lane] + fmaf(Lx8[b], wxc, bbc);
  }
  half8 hp = (statepk + lane)[m * 64];
  half8 uu = (upk + lane)[m * 64];
  half8 np;
  float* op = out + (size_t)t * BATCH * NH + m * HID + lane;
  #pragma unroll
  for (int b = 0; b < 8; ++b) {
    float u = (float)uu[b];
    float nh = u * (float)hp[b] + (1.f - u) * fast_tanh(s[b]);
    np[b] = (_Float16)nh;
    op[(size_t)b * NH] = nh;
  }
  (statepk_next + lane)[m * 64] = np;
}

extern "C" void kernel_launch(void* const* d_in, const int* in_sizes, int n_in,
                              void* d_out, int out_size, void* d_ws, size_t ws_size,
                              hipStream_t stream) {
  const float* x  = (const float*)d_in[0];
  const float* L  = (const float*)d_in[1];
  const float* Wg = (const float*)d_in[2];
  const float* bg = (const float*)d_in[3];
  const float* Wc = (const float*)d_in[4];
  const float* bc = (const float*)d_in[5];
  float* out = (float*)d_out;
  float* ws = (float*)d_ws;

  float*    ell_val  = ws;                                      // N*CAP f32
  int*      ell_colh = (int*)(ws + (size_t)N_NODES * CAP);      // N*CAP i32
  _Float16* ell_valh = (_Float16*)(ws + (size_t)2 * N_NODES * CAP); // N*CAP f16
  int*      ell_cnt  = (int*)(ws + (size_t)2 * N_NODES * CAP + N_NODES * CAP / 2); // N
  float* xT  = ws + (size_t)2 * N_NODES * CAP + N_NODES * CAP / 2 + N_NODES;
  float* LxT = xT + (size_t)N_NODES * TB;
  float* fend = LxT + (size_t)N_NODES * TB;
  half8* stA  = (half8*)fend;                                   // N*64 half8 = 2MB
  half8* stB  = stA + (size_t)N_NODES * HID;
  half8* rspk = stB + (size_t)N_NODES * HID;
  half8* upk  = rspk + (size_t)N_NODES * HID;
  _Float16* Wg16 = (_Float16*)(upk + (size_t)N_NODES * HID);    // 128*72 halves
  _Float16* Wc16 = Wg16 + 128 * WS2;                            // 64*72 halves
  float* wgx = (float*)(Wc16 + 64 * WS2);                       // 128 f32
  float* wcx = wgx + 128;                                       // 64 f32

  k_build_ell<<<N_NODES / 4, 256, 0, stream>>>(L, ell_val, ell_valh, ell_colh,
                                               ell_cnt);
  k_prep<<<64, 256, 0, stream>>>(Wg, Wc, Wg16, Wc16, wgx, wcx);
  k_xt<<<256, 256, 0, stream>>>(x, xT);
  k_spmm_x<<<N_NODES / 8, 512, 0, stream>>>(xT, ell_val, ell_colh, ell_cnt, LxT);
  hipMemsetAsync(stA, 0, (size_t)N_NODES * HID * sizeof(half8), stream);

  half8* cur = stA;
  half8* nxt = stB;
  for (int t = 0; t < SEQ; ++t) {
    k_gates<<<N_NODES / 4, 256, 0, stream>>>(cur, LxT, ell_valh, ell_colh,
                                             ell_cnt, Wg16, wgx, bg, rspk, upk,
                                             t);
    k_cand<<<N_NODES / 4, 256, 0, stream>>>(cur, LxT, ell_valh, ell_colh,
                                            ell_cnt, Wc16, wcx, bc, rspk, upk,
                                            nxt, out, t);
    half8* tmp = cur; cur = nxt; nxt = tmp;
  }
}

// Round 11
// 650.937 us; speedup vs baseline: 4.6188x; 1.0599x over previous
//
#include <hip/hip_runtime.h>
#include <math.h>

#define N_NODES 2048
#define HID 64
#define BATCH 8
#define SEQ 32
#define CAP 64           // ELL slots per row (nnz/row ~33, max ~55, padded x8)
#define TB 256           // SEQ*BATCH
#define NH (N_NODES*HID) // 131072 per batch
#define WS2 72           // fp16 W image row stride (halves), 16B-aligned
#define CSA2 132         // f32 C stride (words): even->b128-aligned, 2-way read banks
#define CSB2 68

typedef __attribute__((ext_vector_type(8))) _Float16 half8;
typedef __attribute__((ext_vector_type(2))) _Float16 half2f;
typedef __attribute__((ext_vector_type(8))) _Float16 f16x8;
typedef __attribute__((ext_vector_type(4))) float f32x4;

__device__ __forceinline__ float fast_sig(float s) {
  return 1.f / (1.f + __expf(-s));
}
__device__ __forceinline__ float fast_tanh(float s) {
  float e = __expf(-2.f * fabsf(s));
  float t = 1.f - 2.f * e / (1.f + e);
  return copysignf(t, s);
}

// ---------------- Kernel 0: build padded ELL (colh = col*HID) ---------------
__global__ __launch_bounds__(256) void k_build_ell(
    const float* __restrict__ L, float* __restrict__ ell_val,
    _Float16* __restrict__ ell_valh, int* __restrict__ ell_colh,
    int* __restrict__ ell_cnt) {
  int wave = (blockIdx.x * blockDim.x + threadIdx.x) >> 6;
  int lane = threadIdx.x & 63;
  if (wave >= N_NODES) return;
  const float* row = L + (size_t)wave * N_NODES;
  int base = 0;
  for (int c = 0; c < N_NODES / 64; ++c) {
    int col = c * 64 + lane;
    float v = row[col];
    bool nz = (v != 0.0f);
    unsigned long long mask = __ballot(nz);
    int before = __popcll(mask & ((1ull << lane) - 1ull));
    if (nz) {
      int slot = base + before;
      if (slot < CAP) {
        ell_colh[wave * CAP + slot] = col * HID;
        ell_val[wave * CAP + slot] = v;
        ell_valh[wave * CAP + slot] = (_Float16)v;
      }
    }
    base += __popcll(mask);
  }
  if (base > CAP) base = CAP;
  int pad = (base + 7) & ~7;
  if (pad > CAP) pad = CAP;
  for (int s = base + lane; s < pad; s += 64) {
    ell_colh[wave * CAP + s] = 0;
    ell_val[wave * CAP + s] = 0.f;
    ell_valh[wave * CAP + s] = (_Float16)0.f;
  }
  if (lane == 0) ell_cnt[wave] = pad;
}

// ---------------- Prolog: pre-swizzled fp16 W images + wx arrays ------------
__global__ __launch_bounds__(256) void k_prep(
    const float* __restrict__ Wg, const float* __restrict__ Wc,
    _Float16* __restrict__ Wg16, _Float16* __restrict__ Wc16,
    float* __restrict__ wgx, float* __restrict__ wcx) {
  int tid = blockIdx.x * blockDim.x + threadIdx.x;
  int nthr = gridDim.x * blockDim.x;
  for (int i = tid; i < 128 * WS2; i += nthr) {
    int o = i / WS2, h = i % WS2;
    Wg16[i] = (h < 64) ? (_Float16)Wg[o * 65 + 1 + h] : (_Float16)0.f;
  }
  for (int i = tid; i < 64 * WS2; i += nthr) {
    int o = i / WS2, h = i % WS2;
    Wc16[i] = (h < 64) ? (_Float16)Wc[o * 65 + 1 + h] : (_Float16)0.f;
  }
  if (tid < 128) wgx[tid] = Wg[tid * 65];
  else if (tid < 192) wcx[tid - 128] = Wc[(tid - 128) * 65];
}

// ---------------- Transpose x[b][t][n] -> xT[n][tb],  tb = t*8 + b ----------
__global__ __launch_bounds__(256) void k_xt(const float* __restrict__ x,
                                            float* __restrict__ xT) {
  __shared__ float s[32][65];
  int n0  = (blockIdx.x & 63) * 32;
  int tb0 = (blockIdx.x >> 6) * 64;
  for (int idx = threadIdx.x; idx < 32 * 64; idx += 256) {
    int ln = idx & 31, ltb = idx >> 5;
    int tb = tb0 + ltb; int b = tb & 7, t = tb >> 3;
    s[ln][ltb] = x[((size_t)b * SEQ + t) * N_NODES + n0 + ln];
  }
  __syncthreads();
  for (int idx = threadIdx.x; idx < 32 * 64; idx += 256) {
    int ln = idx >> 6, ltb = idx & 63;
    xT[(size_t)(n0 + ln) * TB + tb0 + ltb] = s[ln][ltb];
  }
}

// ---------------- LxT[m][tb] = sum_n L[m,n] * xT[n][tb] ---------------------
__global__ __launch_bounds__(512) void k_spmm_x(
    const float* __restrict__ xT, const float* __restrict__ ell_val,
    const int* __restrict__ ell_colh, const int* __restrict__ ell_cnt,
    float* __restrict__ LxT) {
  int m = (blockIdx.x * blockDim.x + threadIdx.x) >> 6;
  int lane = threadIdx.x & 63;
  if (m >= N_NODES) return;
  const int* cp = ell_colh + m * CAP;
  const float* vp = ell_val + m * CAP;
  int cnt = ell_cnt[m];
  float4 acc = {0.f, 0.f, 0.f, 0.f};
  for (int k = 0; k < cnt; k += 4) {
    int4 c = *(const int4*)(cp + k);
    float4 v = *(const float4*)(vp + k);
    float4 xa = *(const float4*)&xT[(size_t)c.x * 4 + lane * 4];
    float4 xb = *(const float4*)&xT[(size_t)c.y * 4 + lane * 4];
    float4 xc = *(const float4*)&xT[(size_t)c.z * 4 + lane * 4];
    float4 xd = *(const float4*)&xT[(size_t)c.w * 4 + lane * 4];
    acc.x = fmaf(v.x, xa.x, acc.x); acc.y = fmaf(v.x, xa.y, acc.y);
    acc.z = fmaf(v.x, xa.z, acc.z); acc.w = fmaf(v.x, xa.w, acc.w);
    acc.x = fmaf(v.y, xb.x, acc.x); acc.y = fmaf(v.y, xb.y, acc.y);
    acc.z = fmaf(v.y, xb.z, acc.z); acc.w = fmaf(v.y, xb.w, acc.w);
    acc.x = fmaf(v.z, xc.x, acc.x); acc.y = fmaf(v.z, xc.y, acc.y);
    acc.z = fmaf(v.z, xc.z, acc.z); acc.w = fmaf(v.z, xc.w, acc.w);
    acc.x = fmaf(v.w, xd.x, acc.x); acc.y = fmaf(v.w, xd.y, acc.y);
    acc.z = fmaf(v.w, xd.z, acc.z); acc.w = fmaf(v.w, xd.w, acc.w);
  }
  *(float4*)&LxT[(size_t)m * TB + lane * 4] = acc;
}

// ---------------- Kernel 1: gates (fp16 gather + MFMA, W from global) -------
__global__ __launch_bounds__(256, 4) void k_gates(
    const half8* __restrict__ statepk, const float* __restrict__ LxT,
    const _Float16* __restrict__ ell_valh, const int* __restrict__ ell_colh,
    const int* __restrict__ ell_cnt, const _Float16* __restrict__ Wg16,
    const float* __restrict__ wgx, const float* __restrict__ bg,
    half8* __restrict__ rspk, half8* __restrict__ upk, int t) {
  __shared__ __align__(16) _Float16 sdiff[32 * WS2];
  __shared__ __align__(16) float sC[32 * CSA2];
  int wv = threadIdx.x >> 6, lane = threadIdx.x & 63;
  int m = blockIdx.x * 4 + wv;
  const half8* pk = statepk + lane;
  const int* cp = ell_colh + m * CAP;
  const _Float16* vp = ell_valh + m * CAP;
  int cnt = ell_cnt[m];
  int l15 = lane & 15, lq = lane >> 4;
  // prefetch A-fragments (L2-hot, hidden behind gather)
  f16x8 afrag[2][2];
  {
    int ot0 = (wv * 4) >> 1;       // = wv*2
    #pragma unroll
    for (int oo = 0; oo < 2; ++oo)
      #pragma unroll
      for (int s = 0; s < 2; ++s)
        afrag[oo][s] = *(const f16x8*)&Wg16[((ot0 + oo) * 16 + l15) * WS2 +
                                            s * 32 + lq * 8];
  }
  half2f a01 = {0, 0}, a23 = {0, 0}, a45 = {0, 0}, a67 = {0, 0};
  for (int k = 0; k < cnt; k += 8) {
    int4 ca = *(const int4*)(cp + k);
    int4 cb = *(const int4*)(cp + k + 4);
    half8 vv = *(const half8*)(vp + k);
#define GATH(C, V) { half8 hv = pk[C]; \
    const half2f* h2 = (const half2f*)&hv; \
    half2f vs = {V, V}; \
    a01 += vs * h2[0]; a23 += vs * h2[1]; \
    a45 += vs * h2[2]; a67 += vs * h2[3]; }
    GATH(ca.x, vv[0]) GATH(ca.y, vv[1]) GATH(ca.z, vv[2]) GATH(ca.w, vv[3])
    GATH(cb.x, vv[4]) GATH(cb.y, vv[5]) GATH(cb.z, vv[6]) GATH(cb.w, vv[7])
#undef GATH
  }
  {
    int r0 = wv * 8;
    sdiff[(r0 + 0) * WS2 + lane] = a01[0];
    sdiff[(r0 + 1) * WS2 + lane] = a01[1];
    sdiff[(r0 + 2) * WS2 + lane] = a23[0];
    sdiff[(r0 + 3) * WS2 + lane] = a23[1];
    sdiff[(r0 + 4) * WS2 + lane] = a45[0];
    sdiff[(r0 + 5) * WS2 + lane] = a45[1];
    sdiff[(r0 + 6) * WS2 + lane] = a67[0];
    sdiff[(r0 + 7) * WS2 + lane] = a67[1];
  }
  __syncthreads();
  #pragma unroll
  for (int tt = 0; tt < 4; ++tt) {
    int tid = wv * 4 + tt;
    int ot = tid >> 1, rt = tid & 1;
    f32x4 acc = {0.f, 0.f, 0.f, 0.f};
    #pragma unroll
    for (int s = 0; s < 2; ++s) {
      f16x8 bf = *(const f16x8*)&sdiff[(rt * 16 + l15) * WS2 + s * 32 + lq * 8];
      acc = __builtin_amdgcn_mfma_f32_16x16x32_f16(afrag[tt >> 1][s], bf, acc,
                                                   0, 0, 0);
    }
    int R = rt * 16 + l15;
    int O = ot * 16 + lq * 4;
    *(f32x4*)&sC[R * CSA2 + O] = acc;
  }
  __syncthreads();
  float4 LxLo = *(const float4*)&LxT[(size_t)m * TB + t * BATCH];
  float4 LxHi = *(const float4*)&LxT[(size_t)m * TB + t * BATCH + 4];
  float Lx8[8] = {LxLo.x, LxLo.y, LxLo.z, LxLo.w,
                  LxHi.x, LxHi.y, LxHi.z, LxHi.w};
  int o0 = lane, o1 = lane + 64;
  float wx0 = wgx[o0], bg0 = bg[o0];
  float wx1 = wgx[o1], bg1 = bg[o1];
  float s0[8], s1[8];
  #pragma unroll
  for (int b = 0; b < 8; ++b) {
    int R = wv * 8 + b;
    s0[b] = sC[R * CSA2 + o0] + fmaf(Lx8[b], wx0, bg0);
    s1[b] = sC[R * CSA2 + o1] + fmaf(Lx8[b], wx1, bg1);
  }
  if (m < N_NODES / 2) {
    // r-half: flat gate idx == flat state idx (rep0 -> node 2m, rep1 -> 2m+1)
    half8 sp0 = pk[m * 128];
    half8 sp1 = pk[m * 128 + 64];
    half8 r0, r1;
    #pragma unroll
    for (int b = 0; b < 8; ++b) {
      r0[b] = (_Float16)(fast_sig(s0[b]) * (float)sp0[b]);
      r1[b] = (_Float16)(fast_sig(s1[b]) * (float)sp1[b]);
    }
    half8* rp = rspk + lane;
    rp[m * 128] = r0;
    rp[m * 128 + 64] = r1;
  } else {
    int mm = m - N_NODES / 2;
    half8 u0, u1;
    #pragma unroll
    for (int b = 0; b < 8; ++b) {
      u0[b] = (_Float16)fast_sig(s0[b]);
      u1[b] = (_Float16)fast_sig(s1[b]);
    }
    half8* up2 = upk + lane;
    up2[mm * 128] = u0;
    up2[mm * 128 + 64] = u1;
  }
}

// ---------------- Kernel 2: cand + GRU update (W from global) ---------------
__global__ __launch_bounds__(256, 4) void k_cand(
    const half8* __restrict__ statepk, const float* __restrict__ LxT,
    const _Float16* __restrict__ ell_valh, const int* __restrict__ ell_colh,
    const int* __restrict__ ell_cnt, const _Float16* __restrict__ Wc16,
    const float* __restrict__ wcx, const float* __restrict__ bc,
    const half8* __restrict__ rspk, const half8* __restrict__ upk,
    half8* __restrict__ statepk_next, float* __restrict__ out, int t) {
  __shared__ __align__(16) _Float16 sdiff[32 * WS2];
  __shared__ __align__(16) float sC[32 * CSB2];
  int wv = threadIdx.x >> 6, lane = threadIdx.x & 63;
  int m = blockIdx.x * 4 + wv;
  const half8* rk = rspk + lane;
  const int* cp = ell_colh + m * CAP;
  const _Float16* vp = ell_valh + m * CAP;
  int cnt = ell_cnt[m];
  int l15 = lane & 15, lq = lane >> 4;
  f16x8 afrag[2];
  #pragma unroll
  for (int s = 0; s < 2; ++s)
    afrag[s] = *(const f16x8*)&Wc16[(wv * 16 + l15) * WS2 + s * 32 + lq * 8];
  half2f a01 = {0, 0}, a23 = {0, 0}, a45 = {0, 0}, a67 = {0, 0};
  for (int k = 0; k < cnt; k += 8) {
    int4 ca = *(const int4*)(cp + k);
    int4 cb = *(const int4*)(cp + k + 4);
    half8 vv = *(const half8*)(vp + k);
#define GATH(C, V) { half8 hv = rk[C]; \
    const half2f* h2 = (const half2f*)&hv; \
    half2f vs = {V, V}; \
    a01 += vs * h2[0]; a23 += vs * h2[1]; \
    a45 += vs * h2[2]; a67 += vs * h2[3]; }
    GATH(ca.x, vv[0]) GATH(ca.y, vv[1]) GATH(ca.z, vv[2]) GATH(ca.w, vv[3])
    GATH(cb.x, vv[4]) GATH(cb.y, vv[5]) GATH(cb.z, vv[6]) GATH(cb.w, vv[7])
#undef GATH
  }
  {
    int r0 = wv * 8;
    sdiff[(r0 + 0) * WS2 + lane] = a01[0];
    sdiff[(r0 + 1) * WS2 + lane] = a01[1];
    sdiff[(r0 + 2) * WS2 + lane] = a23[0];
    sdiff[(r0 + 3) * WS2 + lane] = a23[1];
    sdiff[(r0 + 4) * WS2 + lane] = a45[0];
    sdiff[(r0 + 5) * WS2 + lane] = a45[1];
    sdiff[(r0 + 6) * WS2 + lane] = a67[0];
    sdiff[(r0 + 7) * WS2 + lane] = a67[1];
  }
  __syncthreads();
  #pragma unroll
  for (int tt = 0; tt < 2; ++tt) {
    int rt = tt;                    // ot = wv
    f32x4 acc = {0.f, 0.f, 0.f, 0.f};
    #pragma unroll
    for (int s = 0; s < 2; ++s) {
      f16x8 bf = *(const f16x8*)&sdiff[(rt * 16 + l15) * WS2 + s * 32 + lq * 8];
      acc = __builtin_amdgcn_mfma_f32_16x16x32_f16(afrag[s], bf, acc, 0, 0, 0);
    }
    int R = rt * 16 + l15;
    int O = wv * 16 + lq * 4;
    *(f32x4*)&sC[R * CSB2 + O] = acc;
  }
  __syncthreads();
  float4 LxLo = *(const float4*)&LxT[(size_t)m * TB + t * BATCH];
  float4 LxHi = *(const float4*)&LxT[(size_t)m * TB + t * BATCH + 4];
  float Lx8[8] = {LxLo.x, LxLo.y, LxLo.z, LxLo.w,
                  LxHi.x, LxHi.y, LxHi.z, LxHi.w};
  float wxc = wcx[lane], bbc = bc[lane];
  float s[8];
  #pragma unroll
  for (int b = 0; b < 8; ++b) {
    int R = wv * 8 + b;
    s[b] = sC[R * CSB2 + lane] + fmaf(Lx8[b], wxc, bbc);
  }
  half8 hp = (statepk + lane)[m * 64];
  half8 uu = (upk + lane)[m * 64];
  half8 np;
  float* op = out + (size_t)t * BATCH * NH + m * HID + lane;
  #pragma unroll
  for (int b = 0; b < 8; ++b) {
    float u = (float)uu[b];
    float nh = u * (float)hp[b] + (1.f - u) * fast_tanh(s[b]);
    np[b] = (_Float16)nh;
    op[(size_t)b * NH] = nh;
  }
  (statepk_next + lane)[m * 64] = np;
}

extern "C" void kernel_launch(void* const* d_in, const int* in_sizes, int n_in,
                              void* d_out, int out_size, void* d_ws, size_t ws_size,
                              hipStream_t stream) {
  const float* x  = (const float*)d_in[0];
  const float* L  = (const float*)d_in[1];
  const float* Wg = (const float*)d_in[2];
  const float* bg = (const float*)d_in[3];
  const float* Wc = (const float*)d_in[4];
  const float* bc = (const float*)d_in[5];
  float* out = (float*)d_out;
  float* ws = (float*)d_ws;

  float*    ell_val  = ws;                                      // N*CAP f32
  int*      ell_colh = (int*)(ws + (size_t)N_NODES * CAP);      // N*CAP i32
  _Float16* ell_valh = (_Float16*)(ws + (size_t)2 * N_NODES * CAP); // N*CAP f16
  int*      ell_cnt  = (int*)(ws + (size_t)2 * N_NODES * CAP + N_NODES * CAP / 2); // N
  float* xT  = ws + (size_t)2 * N_NODES * CAP + N_NODES * CAP / 2 + N_NODES;
  float* LxT = xT + (size_t)N_NODES * TB;
  float* fend = LxT + (size_t)N_NODES * TB;
  half8* stA  = (half8*)fend;                                   // N*64 half8 = 2MB
  half8* stB  = stA + (size_t)N_NODES * HID;
  half8* rspk = stB + (size_t)N_NODES * HID;
  half8* upk  = rspk + (size_t)N_NODES * HID;
  _Float16* Wg16 = (_Float16*)(upk + (size_t)N_NODES * HID);    // 128*72 halves
  _Float16* Wc16 = Wg16 + 128 * WS2;                            // 64*72 halves
  float* wgx = (float*)(Wc16 + 64 * WS2);                       // 128 f32
  float* wcx = wgx + 128;                                       // 64 f32

  k_build_ell<<<N_NODES / 4, 256, 0, stream>>>(L, ell_val, ell_valh, ell_colh,
                                               ell_cnt);
  k_prep<<<64, 256, 0, stream>>>(Wg, Wc, Wg16, Wc16, wgx, wcx);
  k_xt<<<256, 256, 0, stream>>>(x, xT);
  k_spmm_x<<<N_NODES / 8, 512, 0, stream>>>(xT, ell_val, ell_colh, ell_cnt, LxT);
  hipMemsetAsync(stA, 0, (size_t)N_NODES * HID * sizeof(half8), stream);

  half8* cur = stA;
  half8* nxt = stB;
  for (int t = 0; t < SEQ; ++t) {
    k_gates<<<N_NODES / 4, 256, 0, stream>>>(cur, LxT, ell_valh, ell_colh,
                                             ell_cnt, Wg16, wgx, bg, rspk, upk,
                                             t);
    k_cand<<<N_NODES / 4, 256, 0, stream>>>(cur, LxT, ell_valh, ell_colh,
                                            ell_cnt, Wc16, wcx, bc, rspk, upk,
                                            nxt, out, t);
    half8* tmp = cur; cur = nxt; nxt = tmp;
  }
}